// Round 1
// baseline (856.088 us; speedup 1.0000x reference)
//
#include <hip/hip_runtime.h>

#define H 64
#define FN 5

// ---------------- CSR build ----------------

__global__ void k_degree(const int* __restrict__ dst, int* __restrict__ counts, int nE) {
    int e = blockIdx.x * 256 + threadIdx.x;
    if (e < nE) atomicAdd(&counts[dst[e]], 1);
}

__global__ void k_scan1(const int* __restrict__ counts, int* __restrict__ row_ptr,
                        int* __restrict__ blockSums, int n) {
    __shared__ int tmp[256];
    int t = threadIdx.x;
    int i = blockIdx.x * 256 + t;
    int v = (i < n) ? counts[i] : 0;
    tmp[t] = v;
    __syncthreads();
    for (int s = 1; s < 256; s <<= 1) {
        int a = (t >= s) ? tmp[t - s] : 0;
        __syncthreads();
        tmp[t] += a;
        __syncthreads();
    }
    if (i < n) row_ptr[i] = tmp[t] - v;   // exclusive within block
    if (t == 255) blockSums[blockIdx.x] = tmp[255];
}

__global__ void k_scan2(const int* __restrict__ blockSums, int* __restrict__ blockOffs, int nb) {
    __shared__ int tmp[512];
    int t = threadIdx.x;
    int v = (t < nb) ? blockSums[t] : 0;
    tmp[t] = v;
    __syncthreads();
    for (int s = 1; s < 512; s <<= 1) {
        int a = (t >= s) ? tmp[t - s] : 0;
        __syncthreads();
        tmp[t] += a;
        __syncthreads();
    }
    if (t < nb) blockOffs[t] = tmp[t] - v;  // exclusive
}

__global__ void k_scan3(int* __restrict__ row_ptr, const int* __restrict__ blockOffs,
                        int n, int nE) {
    int i = blockIdx.x * 256 + threadIdx.x;
    if (i < n) row_ptr[i] += blockOffs[i >> 8];
    if (i == 0) row_ptr[n] = nE;
}

__global__ void k_fill(const int* __restrict__ src, const int* __restrict__ dst,
                       const int* __restrict__ row_ptr, int* __restrict__ cursor,
                       int* __restrict__ csr_src, int nE) {
    int e = blockIdx.x * 256 + threadIdx.x;
    if (e >= nE) return;
    int d = dst[e];
    int pos = row_ptr[d] + atomicAdd(&cursor[d], 1);
    csr_src[pos] = src[e];
}

__global__ void k_dinv(const int* __restrict__ counts, float* __restrict__ dinv, int n) {
    int i = blockIdx.x * 256 + threadIdx.x;
    if (i < n) dinv[i] = 1.0f / sqrtf((float)counts[i] + 1.0f);
}

// ---------------- node encoder: h = relu(x @ Wn + bn) ----------------
// thread = (node, channel); all 64 lanes of a wave share a node -> x reads are
// wave-uniform (scalar-load), Wn reads coalesced & L1-resident.
__global__ void k_encoder(const float* __restrict__ x, const float* __restrict__ Wn,
                          const float* __restrict__ bn, float* __restrict__ h, int n) {
    int tid = blockIdx.x * 256 + threadIdx.x;
    int node = tid >> 6, ch = tid & 63;
    if (node >= n) return;
    float acc = bn[ch];
#pragma unroll
    for (int k = 0; k < FN; ++k)
        acc += x[(size_t)node * FN + k] * Wn[k * H + ch];
    h[(size_t)node * H + ch] = fmaxf(acc, 0.f);
}

// ---------------- g = dinv[:,None] * (h @ W) ----------------
// block 256: 16 rows/block, thread t -> row t>>4, cols [(t&15)*4 .. +3].
// W staged in LDS (16 KB); A rows staged with stride 68 so the four row-groups
// of a wave hit distinct banks on the broadcast a[k] read.
__global__ void k_gemm(const float* __restrict__ h, const float* __restrict__ W,
                       const float* __restrict__ dinv, float* __restrict__ g, int n) {
    __shared__ float Ws[H * H];
    __shared__ float As[16 * 68];
    int t = threadIdx.x;
    // stage W (4096 floats) as float4
    {
        const float4* W4 = (const float4*)W;
        float4* Ws4 = (float4*)Ws;
#pragma unroll
        for (int i = 0; i < 4; ++i) Ws4[t + 256 * i] = W4[t + 256 * i];
    }
    int row0 = blockIdx.x * 16;
    // stage A (16 rows x 64), coalesced global reads
    for (int idx = t; idx < 16 * H; idx += 256) {
        int r = idx >> 6, k = idx & 63;
        int row = row0 + r;
        As[r * 68 + k] = (row < n) ? h[(size_t)row * H + k] : 0.f;
    }
    __syncthreads();

    int r = t >> 4;
    int j4 = (t & 15) * 4;
    int row = row0 + r;
    float4 acc = make_float4(0.f, 0.f, 0.f, 0.f);
    const float* a = As + r * 68;
#pragma unroll
    for (int k = 0; k < H; ++k) {
        float ak = a[k];
        float4 w = *(const float4*)(Ws + k * H + j4);
        acc.x += ak * w.x; acc.y += ak * w.y; acc.z += ak * w.z; acc.w += ak * w.w;
    }
    if (row < n) {
        float d = dinv[row];
        float4 o = make_float4(acc.x * d, acc.y * d, acc.z * d, acc.w * d);
        *(float4*)(g + (size_t)row * H + j4) = o;
    }
}

// ---------------- aggregation: h = relu(dinv[i]*(sum_in g[src] + g[i]) + bc) ----------------
// wave per node, lane = channel: 256 B coalesced gather per edge, no atomics.
__global__ void k_agg(const float* __restrict__ g, const int* __restrict__ csr_src,
                      const int* __restrict__ row_ptr, const float* __restrict__ dinv,
                      const float* __restrict__ bias, float* __restrict__ hout, int n) {
    int gt = blockIdx.x * 256 + threadIdx.x;
    int node = gt >> 6;
    int lane = gt & 63;
    if (node >= n) return;
    float acc = g[(size_t)node * H + lane];   // self term
    int s = row_ptr[node], e = row_ptr[node + 1];
    for (int i = s; i < e; ++i) {
        int srcn = csr_src[i];
        acc += g[(size_t)srcn * H + lane];
    }
    hout[(size_t)node * H + lane] = fmaxf(acc * dinv[node] + bias[lane], 0.f);
}

// ---------------- heads: demand/inventory = relu(h@W1+b1)@W2+b2 ----------------
// one wave per 64 nodes; stage 64 h-rows via LDS (coalesced), lane = node.
// Weight reads are wave-uniform -> scalar loads.
__global__ void k_heads(const float* __restrict__ h,
                        const float* __restrict__ Wd1, const float* __restrict__ bd1,
                        const float* __restrict__ Wd2, const float* __restrict__ bd2,
                        const float* __restrict__ Wi1, const float* __restrict__ bi1,
                        const float* __restrict__ Wi2, const float* __restrict__ bi2,
                        float* __restrict__ out, int n) {
    __shared__ float hs[64 * 65];
    int lane = threadIdx.x;          // blockDim = 64
    int base = blockIdx.x * 64;
    for (int r = 0; r < 64; ++r) {
        int row = base + r;
        hs[r * 65 + lane] = (row < n) ? h[(size_t)row * H + lane] : 0.f;
    }
    __syncthreads();

    float accd[32], acci[32];
#pragma unroll
    for (int j = 0; j < 32; ++j) { accd[j] = bd1[j]; acci[j] = bi1[j]; }
    for (int k = 0; k < H; ++k) {
        float hk = hs[lane * 65 + k];
#pragma unroll
        for (int j = 0; j < 32; ++j) {
            accd[j] += hk * Wd1[k * 32 + j];
            acci[j] += hk * Wi1[k * 32 + j];
        }
    }
    float demand = bd2[0], inventory = bi2[0];
#pragma unroll
    for (int j = 0; j < 32; ++j) {
        demand    += fmaxf(accd[j], 0.f) * Wd2[j];
        inventory += fmaxf(acci[j], 0.f) * Wi2[j];
    }
    int node = base + lane;
    if (node < n) {
        out[node] = demand;
        out[n + node] = inventory;
    }
}

extern "C" void kernel_launch(void* const* d_in, const int* in_sizes, int n_in,
                              void* d_out, int out_size, void* d_ws, size_t ws_size,
                              hipStream_t stream) {
    const float* x   = (const float*)d_in[0];
    const int*   ei  = (const int*)  d_in[1];
    // d_in[2] = edge_attr, d_in[5] = We, d_in[6] = be : dead code in reference, skipped.
    const float* Wn  = (const float*)d_in[3];
    const float* bn  = (const float*)d_in[4];
    const float* Wc  = (const float*)d_in[7];   // [3,64,64]
    const float* bc  = (const float*)d_in[8];   // [3,64]
    const float* Wd1 = (const float*)d_in[9];
    const float* bd1 = (const float*)d_in[10];
    const float* Wd2 = (const float*)d_in[11];
    const float* bd2 = (const float*)d_in[12];
    const float* Wi1 = (const float*)d_in[13];
    const float* bi1 = (const float*)d_in[14];
    const float* Wi2 = (const float*)d_in[15];
    const float* bi2 = (const float*)d_in[16];

    const int n  = in_sizes[0] / FN;   // 100000
    const int nE = in_sizes[1] / 2;    // 1600000
    const int* src = ei;
    const int* dst = ei + nE;

    // workspace layout (all regions 16B-aligned)
    char* w = (char*)d_ws;
    int* counts    = (int*)w;  w += (size_t)n * 4;
    int* cursor    = (int*)w;  w += (size_t)n * 4;
    int* row_ptr   = (int*)w;  w += (size_t)(n + 4) * 4;
    int* blockSums = (int*)w;  w += 2048;
    int* blockOffs = (int*)w;  w += 2048;
    int* csr_src   = (int*)w;  w += (size_t)nE * 4;
    float* dinv    = (float*)w; w += (size_t)n * 4;
    float* hbuf    = (float*)w; w += (size_t)n * H * 4;
    float* gbuf    = (float*)w; w += (size_t)n * H * 4;

    const int nbN = (n + 255) / 256;     // 391
    const int nbE = (nE + 255) / 256;    // 6250

    // zero counts + cursor (adjacent)
    hipMemsetAsync(counts, 0, (size_t)n * 8, stream);

    k_degree<<<nbE, 256, 0, stream>>>(dst, counts, nE);
    k_scan1 <<<nbN, 256, 0, stream>>>(counts, row_ptr, blockSums, n);
    k_scan2 <<<1,   512, 0, stream>>>(blockSums, blockOffs, nbN);
    k_scan3 <<<nbN, 256, 0, stream>>>(row_ptr, blockOffs, n, nE);
    k_fill  <<<nbE, 256, 0, stream>>>(src, dst, row_ptr, cursor, csr_src, nE);
    k_dinv  <<<nbN, 256, 0, stream>>>(counts, dinv, n);

    k_encoder<<<((size_t)n * H + 255) / 256, 256, 0, stream>>>(x, Wn, bn, hbuf, n);

    for (int l = 0; l < 3; ++l) {
        k_gemm<<<(n + 15) / 16, 256, 0, stream>>>(hbuf, Wc + (size_t)l * H * H, dinv, gbuf, n);
        k_agg <<<(n + 3) / 4,  256, 0, stream>>>(gbuf, csr_src, row_ptr, dinv,
                                                 bc + (size_t)l * H, hbuf, n);
    }

    k_heads<<<(n + 63) / 64, 64, 0, stream>>>(hbuf, Wd1, bd1, Wd2, bd2,
                                              Wi1, bi1, Wi2, bi2, (float*)d_out, n);
}

// Round 2
// 608.063 us; speedup vs baseline: 1.4079x; 1.4079x over previous
//
#include <hip/hip_runtime.h>

#define H 64
#define FN 5

// ---------------- CSR build ----------------

__global__ void k_degree(const int* __restrict__ dst, int* __restrict__ counts, int nE) {
    int e = blockIdx.x * 256 + threadIdx.x;
    if (e < nE) atomicAdd(&counts[dst[e]], 1);
}

__global__ void k_scan1(const int* __restrict__ counts, int* __restrict__ row_ptr,
                        int* __restrict__ blockSums, int n) {
    __shared__ int tmp[256];
    int t = threadIdx.x;
    int i = blockIdx.x * 256 + t;
    int v = (i < n) ? counts[i] : 0;
    tmp[t] = v;
    __syncthreads();
    for (int s = 1; s < 256; s <<= 1) {
        int a = (t >= s) ? tmp[t - s] : 0;
        __syncthreads();
        tmp[t] += a;
        __syncthreads();
    }
    if (i < n) row_ptr[i] = tmp[t] - v;   // exclusive within block
    if (t == 255) blockSums[blockIdx.x] = tmp[255];
}

__global__ void k_scan2(const int* __restrict__ blockSums, int* __restrict__ blockOffs, int nb) {
    __shared__ int tmp[512];
    int t = threadIdx.x;
    int v = (t < nb) ? blockSums[t] : 0;
    tmp[t] = v;
    __syncthreads();
    for (int s = 1; s < 512; s <<= 1) {
        int a = (t >= s) ? tmp[t - s] : 0;
        __syncthreads();
        tmp[t] += a;
        __syncthreads();
    }
    if (t < nb) blockOffs[t] = tmp[t] - v;  // exclusive
}

__global__ void k_scan3(int* __restrict__ row_ptr, const int* __restrict__ blockOffs,
                        int n, int nE) {
    int i = blockIdx.x * 256 + threadIdx.x;
    if (i < n) row_ptr[i] += blockOffs[i >> 8];
    if (i == 0) row_ptr[n] = nE;
}

__global__ void k_fill(const int* __restrict__ src, const int* __restrict__ dst,
                       const int* __restrict__ row_ptr, int* __restrict__ cursor,
                       int* __restrict__ csr_src, int nE) {
    int e = blockIdx.x * 256 + threadIdx.x;
    if (e >= nE) return;
    int d = dst[e];
    int pos = row_ptr[d] + atomicAdd(&cursor[d], 1);
    csr_src[pos] = src[e];
}

__global__ void k_dinv(const int* __restrict__ counts, float* __restrict__ dinv, int n) {
    int i = blockIdx.x * 256 + threadIdx.x;
    if (i < n) dinv[i] = 1.0f / sqrtf((float)counts[i] + 1.0f);
}

// ---------------- node encoder: h = relu(x @ Wn + bn) ----------------
__global__ void k_encoder(const float* __restrict__ x, const float* __restrict__ Wn,
                          const float* __restrict__ bn, float* __restrict__ h, int n) {
    int tid = blockIdx.x * 256 + threadIdx.x;
    int node = tid >> 6, ch = tid & 63;
    if (node >= n) return;
    float acc = bn[ch];
#pragma unroll
    for (int k = 0; k < FN; ++k)
        acc += x[(size_t)node * FN + k] * Wn[k * H + ch];
    h[(size_t)node * H + ch] = fmaxf(acc, 0.f);
}

// ---------------- g = dinv[:,None] * (h @ W) ----------------
// 64 rows/block, 256 threads as 16x16: thread (ty,tx) computes a 4-row x 4-col
// register tile. LDS ops per k per thread: 4x ds_read_b32 (A, broadcast across
// tx) + 1x ds_read_b128 (W) for 16 FMAs. As stride 68 keeps the four ty-groups
// of a wave on 2-way-aliased banks (free per m136).
__global__ void k_gemm(const float* __restrict__ h, const float* __restrict__ W,
                       const float* __restrict__ dinv, float* __restrict__ g, int n) {
    __shared__ float Ws[H * H];        // 16 KB
    __shared__ float As[64 * 68];      // 17 KB
    int t = threadIdx.x;
    // stage W (4096 floats) as float4
    {
        const float4* W4 = (const float4*)W;
        float4* Ws4 = (float4*)Ws;
#pragma unroll
        for (int i = 0; i < 4; ++i) Ws4[t + 256 * i] = W4[t + 256 * i];
    }
    int row0 = blockIdx.x * 64;
    // stage A: 64 rows x 64 cols = 1024 float4s, 4 per thread, coalesced
#pragma unroll
    for (int i = 0; i < 4; ++i) {
        int idx = t + 256 * i;             // float4 index
        int r = idx >> 4, k4 = (idx & 15) * 4;
        int row = row0 + r;
        float4 v = (row < n) ? *(const float4*)(h + (size_t)row * H + k4)
                             : make_float4(0.f, 0.f, 0.f, 0.f);
        *(float4*)(As + r * 68 + k4) = v;
    }
    __syncthreads();

    int tx = t & 15, ty = t >> 4;
    int c0 = tx * 4;
    const float* a0 = As + (ty * 4 + 0) * 68;
    const float* a1 = As + (ty * 4 + 1) * 68;
    const float* a2 = As + (ty * 4 + 2) * 68;
    const float* a3 = As + (ty * 4 + 3) * 68;
    float4 acc0 = make_float4(0.f, 0.f, 0.f, 0.f);
    float4 acc1 = acc0, acc2 = acc0, acc3 = acc0;
#pragma unroll 16
    for (int k = 0; k < H; ++k) {
        float4 w = *(const float4*)(Ws + k * H + c0);
        float v0 = a0[k], v1 = a1[k], v2 = a2[k], v3 = a3[k];
        acc0.x += v0 * w.x; acc0.y += v0 * w.y; acc0.z += v0 * w.z; acc0.w += v0 * w.w;
        acc1.x += v1 * w.x; acc1.y += v1 * w.y; acc1.z += v1 * w.z; acc1.w += v1 * w.w;
        acc2.x += v2 * w.x; acc2.y += v2 * w.y; acc2.z += v2 * w.z; acc2.w += v2 * w.w;
        acc3.x += v3 * w.x; acc3.y += v3 * w.y; acc3.z += v3 * w.z; acc3.w += v3 * w.w;
    }
    float4 accs[4] = {acc0, acc1, acc2, acc3};
#pragma unroll
    for (int rr = 0; rr < 4; ++rr) {
        int row = row0 + ty * 4 + rr;
        if (row < n) {
            float d = dinv[row];
            float4 o = make_float4(accs[rr].x * d, accs[rr].y * d,
                                   accs[rr].z * d, accs[rr].w * d);
            *(float4*)(g + (size_t)row * H + c0) = o;
        }
    }
}

// ---------------- aggregation: h = relu(dinv[i]*(sum_in g[src] + g[i]) + bc) ----------------
// wave per node, lane = channel. Edge loop unrolled 4x with independent
// accumulators -> 4 gathers in flight per wave (the round-1 version was a
// serial dependent chain, latency-bound at ~2 TB/s).
__global__ void k_agg(const float* __restrict__ g, const int* __restrict__ csr_src,
                      const int* __restrict__ row_ptr, const float* __restrict__ dinv,
                      const float* __restrict__ bias, float* __restrict__ hout, int n) {
    int gt = blockIdx.x * 256 + threadIdx.x;
    int node = gt >> 6;
    int lane = gt & 63;
    if (node >= n) return;
    int s = row_ptr[node], e = row_ptr[node + 1];
    float acc0 = g[(size_t)node * H + lane];   // self term
    float acc1 = 0.f, acc2 = 0.f, acc3 = 0.f;
    int i = s;
    for (; i + 4 <= e; i += 4) {
        int i0 = csr_src[i];
        int i1 = csr_src[i + 1];
        int i2 = csr_src[i + 2];
        int i3 = csr_src[i + 3];
        acc0 += g[(size_t)i0 * H + lane];
        acc1 += g[(size_t)i1 * H + lane];
        acc2 += g[(size_t)i2 * H + lane];
        acc3 += g[(size_t)i3 * H + lane];
    }
    for (; i < e; ++i) acc0 += g[(size_t)csr_src[i] * H + lane];
    float acc = (acc0 + acc1) + (acc2 + acc3);
    hout[(size_t)node * H + lane] = fmaxf(acc * dinv[node] + bias[lane], 0.f);
}

// ---------------- heads ----------------
__global__ void k_heads(const float* __restrict__ h,
                        const float* __restrict__ Wd1, const float* __restrict__ bd1,
                        const float* __restrict__ Wd2, const float* __restrict__ bd2,
                        const float* __restrict__ Wi1, const float* __restrict__ bi1,
                        const float* __restrict__ Wi2, const float* __restrict__ bi2,
                        float* __restrict__ out, int n) {
    __shared__ float hs[64 * 65];
    int lane = threadIdx.x;          // blockDim = 64
    int base = blockIdx.x * 64;
    for (int r = 0; r < 64; ++r) {
        int row = base + r;
        hs[r * 65 + lane] = (row < n) ? h[(size_t)row * H + lane] : 0.f;
    }
    __syncthreads();

    float accd[32], acci[32];
#pragma unroll
    for (int j = 0; j < 32; ++j) { accd[j] = bd1[j]; acci[j] = bi1[j]; }
    for (int k = 0; k < H; ++k) {
        float hk = hs[lane * 65 + k];
#pragma unroll
        for (int j = 0; j < 32; ++j) {
            accd[j] += hk * Wd1[k * 32 + j];
            acci[j] += hk * Wi1[k * 32 + j];
        }
    }
    float demand = bd2[0], inventory = bi2[0];
#pragma unroll
    for (int j = 0; j < 32; ++j) {
        demand    += fmaxf(accd[j], 0.f) * Wd2[j];
        inventory += fmaxf(acci[j], 0.f) * Wi2[j];
    }
    int node = base + lane;
    if (node < n) {
        out[node] = demand;
        out[n + node] = inventory;
    }
}

extern "C" void kernel_launch(void* const* d_in, const int* in_sizes, int n_in,
                              void* d_out, int out_size, void* d_ws, size_t ws_size,
                              hipStream_t stream) {
    const float* x   = (const float*)d_in[0];
    const int*   ei  = (const int*)  d_in[1];
    // d_in[2] = edge_attr, d_in[5] = We, d_in[6] = be : dead code in reference, skipped.
    const float* Wn  = (const float*)d_in[3];
    const float* bn  = (const float*)d_in[4];
    const float* Wc  = (const float*)d_in[7];   // [3,64,64]
    const float* bc  = (const float*)d_in[8];   // [3,64]
    const float* Wd1 = (const float*)d_in[9];
    const float* bd1 = (const float*)d_in[10];
    const float* Wd2 = (const float*)d_in[11];
    const float* bd2 = (const float*)d_in[12];
    const float* Wi1 = (const float*)d_in[13];
    const float* bi1 = (const float*)d_in[14];
    const float* Wi2 = (const float*)d_in[15];
    const float* bi2 = (const float*)d_in[16];

    const int n  = in_sizes[0] / FN;   // 100000
    const int nE = in_sizes[1] / 2;    // 1600000
    const int* src = ei;
    const int* dst = ei + nE;

    // workspace layout (all regions 16B-aligned)
    char* w = (char*)d_ws;
    int* counts    = (int*)w;  w += (size_t)n * 4;
    int* cursor    = (int*)w;  w += (size_t)n * 4;
    int* row_ptr   = (int*)w;  w += (size_t)(n + 4) * 4;
    int* blockSums = (int*)w;  w += 2048;
    int* blockOffs = (int*)w;  w += 2048;
    int* csr_src   = (int*)w;  w += (size_t)nE * 4;
    float* dinv    = (float*)w; w += (size_t)n * 4;
    float* hbuf    = (float*)w; w += (size_t)n * H * 4;
    float* gbuf    = (float*)w; w += (size_t)n * H * 4;

    const int nbN = (n + 255) / 256;     // 391
    const int nbE = (nE + 255) / 256;    // 6250

    // zero counts + cursor (adjacent)
    hipMemsetAsync(counts, 0, (size_t)n * 8, stream);

    k_degree<<<nbE, 256, 0, stream>>>(dst, counts, nE);
    k_scan1 <<<nbN, 256, 0, stream>>>(counts, row_ptr, blockSums, n);
    k_scan2 <<<1,   512, 0, stream>>>(blockSums, blockOffs, nbN);
    k_scan3 <<<nbN, 256, 0, stream>>>(row_ptr, blockOffs, n, nE);
    k_fill  <<<nbE, 256, 0, stream>>>(src, dst, row_ptr, cursor, csr_src, nE);
    k_dinv  <<<nbN, 256, 0, stream>>>(counts, dinv, n);

    k_encoder<<<((size_t)n * H + 255) / 256, 256, 0, stream>>>(x, Wn, bn, hbuf, n);

    for (int l = 0; l < 3; ++l) {
        k_gemm<<<(n + 63) / 64, 256, 0, stream>>>(hbuf, Wc + (size_t)l * H * H, dinv, gbuf, n);
        k_agg <<<(n + 3) / 4,  256, 0, stream>>>(gbuf, csr_src, row_ptr, dinv,
                                                 bc + (size_t)l * H, hbuf, n);
    }

    k_heads<<<(n + 63) / 64, 64, 0, stream>>>(hbuf, Wd1, bd1, Wd2, bd2,
                                              Wi1, bi1, Wi2, bi2, (float*)d_out, n);
}